// Round 1
// baseline (61.413 us; speedup 1.0000x reference)
//
#include <hip/hip_runtime.h>
#include <hip/hip_bf16.h>
#include <stdint.h>

// Problem constants (B,S,D,K) = (2,4096,512,32)
#define B_SZ   2
#define S_LEN  4096
#define D_DIM  512
#define K_R    32
#define M_ROWS (B_SZ * S_LEN)   // 8192

typedef __attribute__((ext_vector_type(8))) short bf16x8;
typedef __attribute__((ext_vector_type(4))) float f32x4;

// ---------------------------------------------------------------------------
// async global->LDS, 16B per lane. LDS dest is wave-uniform base + lane*16.
// ---------------------------------------------------------------------------
__device__ __forceinline__ void gload_lds16(const void* g, void* lds) {
  __builtin_amdgcn_global_load_lds(
      (__attribute__((address_space(1))) void*)g,
      (__attribute__((address_space(3))) void*)lds, 16, 0, 0);
}

// ---------------------------------------------------------------------------
// Kernel 1: cast x (f32) -> bf16, 8 elements/thread
// ---------------------------------------------------------------------------
__global__ void __launch_bounds__(256) cast_x_kernel(
    const float* __restrict__ x, __hip_bfloat16* __restrict__ xb) {
  const int i = blockIdx.x * 256 + threadIdx.x;   // grid sized exactly
  const float4* xp = (const float4*)x;
  float4 v0 = xp[2 * i];
  float4 v1 = xp[2 * i + 1];
  union { __hip_bfloat16 h[8]; int4 v; } u;
  u.h[0] = __float2bfloat16(v0.x); u.h[1] = __float2bfloat16(v0.y);
  u.h[2] = __float2bfloat16(v0.z); u.h[3] = __float2bfloat16(v0.w);
  u.h[4] = __float2bfloat16(v1.x); u.h[5] = __float2bfloat16(v1.y);
  u.h[6] = __float2bfloat16(v1.z); u.h[7] = __float2bfloat16(v1.w);
  ((int4*)xb)[i] = u.v;
}

// ---------------------------------------------------------------------------
// Kernel 2: Wc = W_in @ W_out (f32 compute), store transposed bf16:
//           WcT[n][k] = Wc[k][n].  32x32 tile per block, 2x2 per thread.
// ---------------------------------------------------------------------------
__global__ void __launch_bounds__(256) wc_kernel(
    const float* __restrict__ Win, const float* __restrict__ Wout,
    __hip_bfloat16* __restrict__ WcT) {
  __shared__ float Asm[32][33];
  __shared__ float Bsm[32][33];
  const int i0 = blockIdx.y * 32;   // rows of Wc (k-dim of GEMM2's B)
  const int j0 = blockIdx.x * 32;   // cols of Wc (n-dim)
  const int t  = threadIdx.x;
  const int lr = t >> 3;            // 0..31
  const int lc = (t & 7) * 4;       // 0,4,...,28
  const int oi = (t >> 4) * 2;      // 0..30
  const int oj = (t & 15) * 2;      // 0..30
  float acc00 = 0.f, acc01 = 0.f, acc10 = 0.f, acc11 = 0.f;
  for (int k0 = 0; k0 < 512; k0 += 32) {
    float4 a = *(const float4*)&Win[(size_t)(i0 + lr) * 512 + k0 + lc];
    float4 b = *(const float4*)&Wout[(size_t)(k0 + lr) * 512 + j0 + lc];
    __syncthreads();  // previous iter's readers done
    Asm[lr][lc] = a.x; Asm[lr][lc + 1] = a.y; Asm[lr][lc + 2] = a.z; Asm[lr][lc + 3] = a.w;
    Bsm[lr][lc] = b.x; Bsm[lr][lc + 1] = b.y; Bsm[lr][lc + 2] = b.z; Bsm[lr][lc + 3] = b.w;
    __syncthreads();
#pragma unroll
    for (int k = 0; k < 32; ++k) {
      const float a0 = Asm[oi][k], a1 = Asm[oi + 1][k];
      const float b0 = Bsm[k][oj], b1 = Bsm[k][oj + 1];
      acc00 = fmaf(a0, b0, acc00); acc01 = fmaf(a0, b1, acc01);
      acc10 = fmaf(a1, b0, acc10); acc11 = fmaf(a1, b1, acc11);
    }
  }
  // WcT[j][i] = Wc[i][j]
  WcT[(size_t)(j0 + oj) * 512 + i0 + oi]         = __float2bfloat16(acc00);
  WcT[(size_t)(j0 + oj) * 512 + i0 + oi + 1]     = __float2bfloat16(acc10);
  WcT[(size_t)(j0 + oj + 1) * 512 + i0 + oi]     = __float2bfloat16(acc01);
  WcT[(size_t)(j0 + oj + 1) * 512 + i0 + oi + 1] = __float2bfloat16(acc11);
}

// ---------------------------------------------------------------------------
// Kernel 3: t = Xb @ Wc   (M=8192, N=512, K=512), bf16 MFMA, f32 out.
//   A = Xb row-major (M x 512), B given as WcT[n][k] (512 x 512).
//   Tile 128x64, BK=32, 4 waves (2x2), each wave 64x32 = 4x2 fragments.
// ---------------------------------------------------------------------------
#define BM 128
#define BN 64
#define BK 32

__global__ void __launch_bounds__(256) gemm_xwc_kernel(
    const __hip_bfloat16* __restrict__ A,
    const __hip_bfloat16* __restrict__ BT,
    float* __restrict__ C) {
  __shared__ __hip_bfloat16 As[BM][BK];   // 8 KB
  __shared__ __hip_bfloat16 Bs[BN][BK];   // 4 KB
  const int tid = threadIdx.x;
  const int w = tid >> 6;
  const int l = tid & 63;

  // XCD-chunked swizzle: 512 blocks = 8 XCDs x 64; same-XCD blocks share bm.
  const int lin = blockIdx.x;
  const int id2 = (lin & 7) * 64 + (lin >> 3);
  const int bm0 = (id2 >> 3) * BM;   // 64 m-tiles
  const int bn0 = (id2 & 7) * BN;    // 8 n-tiles

  const int wr = (w >> 1) * 64;      // wave row in tile
  const int wc = (w & 1) * 32;       // wave col in tile

  f32x4 acc[4][2] = {};

  // staging: lane l writes LDS bytes [base + l*16]; rows are K-contiguous.
  const int srA = w * 32 + (l >> 2);
  const int srB = w * 16 + (l >> 2);
  const int sc  = (l & 3) * 8;
  const __hip_bfloat16* gA = A + (size_t)(bm0 + srA) * 512 + sc;
  const __hip_bfloat16* gB = BT + (size_t)(bn0 + srB) * 512 + sc;
  __hip_bfloat16* ldsA = &As[0][0] + w * 1024;  // wave-uniform
  __hip_bfloat16* ldsB = &Bs[0][0] + w * 512;

  const int fr = l & 15;
  const int fk = (l >> 4) * 8;   // 8 contiguous k per lane

  for (int k0 = 0; k0 < 512; k0 += BK) {
    gload_lds16(gA + k0, ldsA);
    gload_lds16(gA + k0 + 16 * 512, ldsA + 512);
    gload_lds16(gB + k0, ldsB);
    __syncthreads();   // vmcnt(0) drained by barrier -> LDS tile ready
    bf16x8 af[4], bfr[2];
#pragma unroll
    for (int m = 0; m < 4; ++m)
      af[m] = *(const bf16x8*)&As[wr + m * 16 + fr][fk];
#pragma unroll
    for (int n = 0; n < 2; ++n)
      bfr[n] = *(const bf16x8*)&Bs[wc + n * 16 + fr][fk];
#pragma unroll
    for (int m = 0; m < 4; ++m)
#pragma unroll
      for (int n = 0; n < 2; ++n)
        acc[m][n] = __builtin_amdgcn_mfma_f32_16x16x32_bf16(af[m], bfr[n], acc[m][n], 0, 0, 0);
    __syncthreads();   // readers done before next stage overwrites
  }

  // epilogue: C/D layout col = lane&15, row = (lane>>4)*4 + reg (verified m89/m91)
  const int fq = l >> 4;
#pragma unroll
  for (int m = 0; m < 4; ++m)
#pragma unroll
    for (int n = 0; n < 2; ++n)
#pragma unroll
      for (int r = 0; r < 4; ++r) {
        const int grow = bm0 + wr + m * 16 + fq * 4 + r;
        const int gcol = bn0 + wc + n * 16 + fr;
        C[(size_t)grow * 512 + gcol] = acc[m][n][r];
      }
}

// ---------------------------------------------------------------------------
// Kernel 4: out[row,:] = x[row,:] + b_out + sum_k w[s,k] * t[b, routes[s,k], :]
//   one row per 128-thread block (each thread owns one float4 of D=512).
// ---------------------------------------------------------------------------
__global__ void __launch_bounds__(128) fusion_kernel(
    const float* __restrict__ x, const float* __restrict__ t,
    const float* __restrict__ b_out, const float* __restrict__ fw,
    const int* __restrict__ routes, float* __restrict__ out) {
  __shared__ int   r_s[K_R];
  __shared__ float w_s[K_R];
  const int lin = blockIdx.x;
  // XCD-chunked: each XCD handles a contiguous 1024-row span -> gather set L2-fits
  const int row = (lin & 7) * (M_ROWS / 8) + (lin >> 3);
  const int s = row & (S_LEN - 1);
  const int b = row >> 12;   // S = 4096 = 2^12
  if (threadIdx.x < K_R) {
    r_s[threadIdx.x] = routes[s * K_R + threadIdx.x];
    w_s[threadIdx.x] = fw[s * K_R + threadIdx.x];
  }
  __syncthreads();
  const int c = threadIdx.x;   // 0..127
  const float4* tb = (const float4*)t + (size_t)b * S_LEN * (D_DIM / 4);
  float4 acc = make_float4(0.f, 0.f, 0.f, 0.f);
#pragma unroll 8
  for (int k = 0; k < K_R; ++k) {
    const float wk = w_s[k];
    const float4 v = tb[(size_t)r_s[k] * (D_DIM / 4) + c];
    acc.x = fmaf(wk, v.x, acc.x);
    acc.y = fmaf(wk, v.y, acc.y);
    acc.z = fmaf(wk, v.z, acc.z);
    acc.w = fmaf(wk, v.w, acc.w);
  }
  const float4 xr = ((const float4*)x)[(size_t)row * (D_DIM / 4) + c];
  const float4 bb = ((const float4*)b_out)[c];
  float4 o;
  o.x = xr.x + bb.x + acc.x;
  o.y = xr.y + bb.y + acc.y;
  o.z = xr.z + bb.z + acc.z;
  o.w = xr.w + bb.w + acc.w;
  ((float4*)out)[(size_t)row * (D_DIM / 4) + c] = o;
}

// ---------------------------------------------------------------------------
extern "C" void kernel_launch(void* const* d_in, const int* in_sizes, int n_in,
                              void* d_out, int out_size, void* d_ws, size_t ws_size,
                              hipStream_t stream) {
  const float* x      = (const float*)d_in[0];
  const float* W_in   = (const float*)d_in[1];
  const float* W_out  = (const float*)d_in[2];
  const float* b_out  = (const float*)d_in[3];
  const float* fw     = (const float*)d_in[4];
  const int*   routes = (const int*)d_in[5];
  float* out = (float*)d_out;

  // workspace layout: Xb (8 MB) | WcT (512 KB) | t (16 MB)  -> 24.5 MB total
  char* ws = (char*)d_ws;
  __hip_bfloat16* Xb  = (__hip_bfloat16*)ws;
  __hip_bfloat16* WcT = (__hip_bfloat16*)(ws + 8388608);
  float* t            = (float*)(ws + 8912896);

  // 1) x -> bf16                 (4,194,304 elems / 8 per thread / 256)
  cast_x_kernel<<<2048, 256, 0, stream>>>(x, Xb);
  // 2) Wc = W_in@W_out -> WcT bf16
  wc_kernel<<<dim3(16, 16), 256, 0, stream>>>(W_in, W_out, WcT);
  // 3) t = Xb @ Wc (f32 out)
  gemm_xwc_kernel<<<512, 256, 0, stream>>>(Xb, WcT, t);
  // 4) gather-fuse + bias + residual
  fusion_kernel<<<M_ROWS, 128, 0, stream>>>(x, t, b_out, fw, routes, out);
}